// Round 8
// baseline (3978.608 us; speedup 1.0000x reference)
//
#include <hip/hip_runtime.h>

typedef unsigned char u8;
typedef unsigned int u32;

#define T_STEPS 4
#define B_SZ 8
#define C_IN 512
#define CH 2048
#define N_SP 1024
#define S_C ((size_t)B_SZ * C_IN * N_SP)    // elems per timestep

// ---------------------------------------------------------------------------
// lif_x: x [T,B,C,N] fp32 -> xs u8 spikes, same flat layout (round-2 verbatim).
// ---------------------------------------------------------------------------
__global__ __launch_bounds__(256) void lif_x_kernel(const float* __restrict__ in,
                                                    u8* __restrict__ out)
{
    size_t i = (size_t)blockIdx.x * 256 + threadIdx.x;
    float v = 0.0f;
    #pragma unroll
    for (int t = 0; t < T_STEPS; ++t) {
        float x = in[(size_t)t * S_C + i];
        v += (x - v) * 0.5f;
        u8 s = (v >= 0.5f) ? 1 : 0;
        out[(size_t)t * S_C + i] = s;
        v = s ? 0.0f : v;
    }
}

// ---------------------------------------------------------------------------
// Fused GEMM + BN (+bias) + LIF, fp32. Per-output math is ascending-k with a
// single fp32 accumulator -> bit-identical to the round-2/6/7 passing kernels.
// Layouts: X [TB][K][N], W [CO][K] fp32, Y [TB][CO][N].
// MODE 0: LIF -> u8 spikes. MODE 1: y + res -> f32. MODE 2: LIF spike + in-place res -> f32.
// BSRC 0: u8 X. BSRC 1: u8 X * kvsf[k] at staging (proj mask). BSRC 2: f32 X (fc1).
// Tile 64co x 128n, 256 threads, per-thread 4co x 8n (two float4 n-chunks at
// tx*4 and tx*4+64 -> 2-way LDS bank aliasing only). Register prefetch of the
// next k-tile; u8 unpack at staging. nblk = bid & 7 pins n-slices to XCDs.
// ---------------------------------------------------------------------------
template<int MODE, int BSRC, bool BIAS, int K, int CO, int NSEL>
__global__ __launch_bounds__(256, 4) void mm(
    const float* __restrict__ W0, const float* __restrict__ W1, const float* __restrict__ W2,
    const void* __restrict__ Xv,
    const float* __restrict__ bn0, const float* __restrict__ bn1, const float* __restrict__ bn2,
    const float* __restrict__ bias,
    const float* __restrict__ kvsf,
    const float* __restrict__ res,
    void* Y0, void* Y1, void* Y2)
{
    constexpr int BM = 64;
    constexpr int NB_CO = CO / BM;
    constexpr int KT = K / 16;

    __shared__ float As[16][72];      // [k][co]  (stride 72: 2-way reads, free)
    __shared__ float Xs[16][136];     // [k][n]   (stride 136)

    const int bid = blockIdx.x;
    const int nblk = bid & 7;         // XCD-pinned n-slice
    int slot = bid >> 3;
    const int cb = slot % NB_CO; slot /= NB_CO;
    const int sel = (NSEL > 1) ? (slot % NSEL) : 0;
    const int b   = (NSEL > 1) ? (slot / NSEL) : slot;

    const float* W   = (NSEL == 1 || sel == 0) ? W0  : (sel == 1 ? W1  : W2);
    const float* bnp = (NSEL == 1 || sel == 0) ? bn0 : (sel == 1 ? bn1 : bn2);
    void* Yv         = (NSEL == 1 || sel == 0) ? Y0  : (sel == 1 ? Y1  : Y2);

    const int coBase = cb * BM;
    const int n0blk = nblk * 128;
    const int tid = threadIdx.x;
    const int tx = tid & 15, ty = tid >> 4;

    // staging indices: W rows by tid>>2, X row = ty, X cols = tx*4 / tx*4+64
    const int wr = tid >> 2;
    const int wk4 = (tid & 3) * 4;

    // BN constants (round-2 expressions)
    float scale[4], shift[4];
    #pragma unroll
    for (int i = 0; i < 4; ++i) {
        const int co = coBase + ty * 4 + i;
        const float g = bnp[co], be = bnp[CO + co];
        const float mn = bnp[2 * CO + co], vr = bnp[3 * CO + co];
        scale[i] = g / sqrtf(vr + 1e-5f);
        shift[i] = be - mn * scale[i];
        if (BIAS) shift[i] += bias[co] * scale[i];
    }

    float vst[4][8];
    if (MODE != 1) {
        #pragma unroll
        for (int i = 0; i < 4; ++i)
            #pragma unroll
            for (int j = 0; j < 8; ++j) vst[i][j] = 0.0f;
    }

    for (int t = 0; t < T_STEPS; ++t) {
        const int tb = t * B_SZ + b;
        const u8* Xu = (const u8*)Xv + (size_t)tb * K * N_SP;
        const float* Xf = (const float*)Xv + (size_t)tb * K * N_SP;

        float acc[4][8];
        #pragma unroll
        for (int i = 0; i < 4; ++i)
            #pragma unroll
            for (int j = 0; j < 8; ++j) acc[i][j] = 0.0f;

        float4 wreg;
        u32 xa, xb;
        float mreg = 1.0f;
        float4 xfa, xfb;

        auto prefetch = [&](int kt) {
            wreg = *reinterpret_cast<const float4*>(
                W + (size_t)(coBase + wr) * K + kt * 16 + wk4);
            if constexpr (BSRC <= 1) {
                const u8* xp = Xu + (size_t)(kt * 16 + ty) * N_SP + n0blk + tx * 4;
                xa = *reinterpret_cast<const u32*>(xp);
                xb = *reinterpret_cast<const u32*>(xp + 64);
                if constexpr (BSRC == 1)
                    mreg = kvsf[(size_t)tb * K + kt * 16 + ty];
            } else {
                const float* xp = Xf + (size_t)(kt * 16 + ty) * N_SP + n0blk + tx * 4;
                xfa = *reinterpret_cast<const float4*>(xp);
                xfb = *reinterpret_cast<const float4*>(xp + 64);
            }
        };

        prefetch(0);

        for (int kt = 0; kt < KT; ++kt) {
            __syncthreads();    // previous tile's compute done; LDS reusable
            As[wk4 + 0][wr] = wreg.x;
            As[wk4 + 1][wr] = wreg.y;
            As[wk4 + 2][wr] = wreg.z;
            As[wk4 + 3][wr] = wreg.w;
            if constexpr (BSRC <= 1) {
                float4 s0, s1;
                s0.x = (float)( xa        & 0xFFu);
                s0.y = (float)((xa >> 8 ) & 0xFFu);
                s0.z = (float)((xa >> 16) & 0xFFu);
                s0.w = (float)( xa >> 24        );
                s1.x = (float)( xb        & 0xFFu);
                s1.y = (float)((xb >> 8 ) & 0xFFu);
                s1.z = (float)((xb >> 16) & 0xFFu);
                s1.w = (float)( xb >> 24        );
                if constexpr (BSRC == 1) {
                    s0.x *= mreg; s0.y *= mreg; s0.z *= mreg; s0.w *= mreg;   // 0/1 x 0/1: exact
                    s1.x *= mreg; s1.y *= mreg; s1.z *= mreg; s1.w *= mreg;
                }
                *reinterpret_cast<float4*>(&Xs[ty][tx * 4]) = s0;
                *reinterpret_cast<float4*>(&Xs[ty][tx * 4 + 64]) = s1;
            } else {
                *reinterpret_cast<float4*>(&Xs[ty][tx * 4]) = xfa;
                *reinterpret_cast<float4*>(&Xs[ty][tx * 4 + 64]) = xfb;
            }
            __syncthreads();
            if (kt + 1 < KT) prefetch(kt + 1);   // overlaps with compute below

            #pragma unroll
            for (int kk = 0; kk < 16; ++kk) {
                float4 av = *reinterpret_cast<const float4*>(&As[kk][ty * 4]);
                float4 x0 = *reinterpret_cast<const float4*>(&Xs[kk][tx * 4]);
                float4 x1 = *reinterpret_cast<const float4*>(&Xs[kk][tx * 4 + 64]);
                float wa[4] = {av.x, av.y, av.z, av.w};
                float xw[8] = {x0.x, x0.y, x0.z, x0.w, x1.x, x1.y, x1.z, x1.w};
                #pragma unroll
                for (int i = 0; i < 4; ++i)
                    #pragma unroll
                    for (int j = 0; j < 8; ++j)
                        acc[i][j] += wa[i] * xw[j];   // ascending-k, single acc
            }
        }

        // epilogue for this timestep (round-2/6/7 expressions, bit-identical).
        // n positions: base (tx*4 + j) and base+64 (j = 4..7).
        #pragma unroll
        for (int i = 0; i < 4; ++i) {
            const int co = coBase + ty * 4 + i;
            const size_t base = ((size_t)tb * CO + co) * N_SP + n0blk + tx * 4;
            if constexpr (MODE == 0) {
                u32 p0 = 0, p1 = 0;
                #pragma unroll
                for (int j = 0; j < 8; ++j) {
                    const float y = acc[i][j] * scale[i] + shift[i];
                    float v = vst[i][j];
                    v += (y - v) * 0.5f;
                    const u32 s = (v >= 0.5f) ? 1u : 0u;
                    vst[i][j] = s ? 0.0f : v;
                    if (j < 4) p0 |= s << (8 * j); else p1 |= s << (8 * (j - 4));
                }
                *reinterpret_cast<u32*>((u8*)Yv + base) = p0;
                *reinterpret_cast<u32*>((u8*)Yv + base + 64) = p1;
            } else if constexpr (MODE == 1) {
                float4 r0 = *reinterpret_cast<const float4*>(res + base);
                float4 r1 = *reinterpret_cast<const float4*>(res + base + 64);
                float rr[8] = {r0.x, r0.y, r0.z, r0.w, r1.x, r1.y, r1.z, r1.w};
                float o[8];
                #pragma unroll
                for (int j = 0; j < 8; ++j)
                    o[j] = acc[i][j] * scale[i] + shift[i] + rr[j];
                float4 s0 = {o[0], o[1], o[2], o[3]};
                float4 s1 = {o[4], o[5], o[6], o[7]};
                *reinterpret_cast<float4*>((float*)Yv + base) = s0;
                *reinterpret_cast<float4*>((float*)Yv + base + 64) = s1;
            } else {
                float* op = (float*)Yv + base;
                float4 r0 = *reinterpret_cast<const float4*>(op);
                float4 r1 = *reinterpret_cast<const float4*>(op + 64);
                float rr[8] = {r0.x, r0.y, r0.z, r0.w, r1.x, r1.y, r1.z, r1.w};
                float o[8];
                #pragma unroll
                for (int j = 0; j < 8; ++j) {
                    const float y = acc[i][j] * scale[i] + shift[i];
                    float v = vst[i][j];
                    v += (y - v) * 0.5f;
                    const u32 s = (v >= 0.5f) ? 1u : 0u;
                    vst[i][j] = s ? 0.0f : v;
                    o[j] = rr[j] + (s ? 1.0f : 0.0f);
                }
                float4 s0 = {o[0], o[1], o[2], o[3]};
                float4 s1 = {o[4], o[5], o[6], o[7]};
                *reinterpret_cast<float4*>(op) = s0;
                *reinterpret_cast<float4*>(op + 64) = s1;
            }
        }
    }
}

// ---------------------------------------------------------------------------
// kv_raw[row=tb*C+c] = sum_n k*v  (exact integer; round-2 verbatim)
// ---------------------------------------------------------------------------
__global__ __launch_bounds__(256) void kv_reduce(const u8* __restrict__ ks,
                                                 const u8* __restrict__ vs,
                                                 float* __restrict__ kv)
{
    const int row = blockIdx.x * 4 + (threadIdx.x >> 6);  // [0, T*B*C)
    const int lane = threadIdx.x & 63;
    const u8* kp = ks + (size_t)row * N_SP;
    const u8* vp = vs + (size_t)row * N_SP;
    int acc = 0;
    #pragma unroll
    for (int n = 0; n < N_SP; n += 256) {
        uchar4 a = *reinterpret_cast<const uchar4*>(kp + n + lane * 4);
        uchar4 c = *reinterpret_cast<const uchar4*>(vp + n + lane * 4);
        acc += (a.x & c.x) + (a.y & c.y) + (a.z & c.z) + (a.w & c.w);
    }
    #pragma unroll
    for (int off = 32; off; off >>= 1) acc += __shfl_down(acc, off, 64);
    if (lane == 0) kv[row] = (float)acc;
}

// ---------------------------------------------------------------------------
// talking heads (8x8 over heads) + LIF -> kvs float {0,1}  (round-2 verbatim)
// ---------------------------------------------------------------------------
__global__ __launch_bounds__(256) void th_lif(const float* __restrict__ kvraw,
                                              const float* __restrict__ th,
                                              float* __restrict__ kvs)
{
    const int i = blockIdx.x * 256 + threadIdx.x;   // [0, B*C)
    const int b = i >> 9;
    const int c = i & 511;
    const int g = c >> 6;
    const int dd = c & 63;
    float v = 0.0f;
    #pragma unroll
    for (int t = 0; t < T_STEPS; ++t) {
        const float* base = kvraw + ((size_t)t * B_SZ + b) * C_IN;
        float x = 0.0f;
        #pragma unroll
        for (int hh = 0; hh < 8; ++hh)
            x += base[hh * 64 + dd] * th[g * 8 + hh];
        v += (x - v) * 0.5f;
        const float s = (v >= 0.5f) ? 1.0f : 0.0f;
        kvs[((size_t)t * B_SZ + b) * C_IN + c] = s;
        v = (s != 0.0f) ? 0.0f : v;
    }
}

extern "C" void kernel_launch(void* const* d_in, const int* in_sizes, int n_in,
                              void* d_out, int out_size, void* d_ws, size_t ws_size,
                              hipStream_t stream)
{
    const float* x       = (const float*)d_in[0];
    const float* q_w     = (const float*)d_in[1];
    const float* q_bn    = (const float*)d_in[2];
    const float* k_w     = (const float*)d_in[3];
    const float* k_bn    = (const float*)d_in[4];
    const float* v_w     = (const float*)d_in[5];
    const float* v_bn    = (const float*)d_in[6];
    const float* th_w    = (const float*)d_in[7];
    const float* proj_w  = (const float*)d_in[8];
    const float* proj_b  = (const float*)d_in[9];
    const float* proj_bn = (const float*)d_in[10];
    const float* fc1_w   = (const float*)d_in[11];
    const float* fc1_b   = (const float*)d_in[12];
    const float* fc1_bn  = (const float*)d_in[13];
    const float* fc2_w   = (const float*)d_in[14];
    const float* fc2_b   = (const float*)d_in[15];
    const float* fc2_bn  = (const float*)d_in[16];
    float* out = (float*)d_out;

    // workspace: round-2/6/7's proven 64 MiB + 128 KiB map
    u8* ws = (u8*)d_ws;
    const size_t SLOT = (size_t)T_STEPS * S_C;        // 16 MiB per u8 slot
    u8* xs = ws;                    // [TB][C][N] u8
    u8* qs = ws + SLOT;
    u8* ks = ws + 2 * SLOT;
    u8* vs = ws + 3 * SLOT;
    float* kvraw = (float*)(ws + 4 * SLOT);                 // [TB][C] f32 (64 KiB)
    float* kvsf  = kvraw + (size_t)T_STEPS * B_SZ * C_IN;   // [TB][C] f32 (64 KiB)
    u8* hdn = ws;                   // [TB][Ch][N] u8 = 64 MiB, reuses xs..vs (dead by fc1)

    // 1. xs = lif(x)
    lif_x_kernel<<<(int)(S_C / 256), 256, 0, stream>>>(x, xs);

    // 2. q/k/v = lif(bn(conv(xs)))  — fused triple GEMM
    //    grid = 8 n-slices * (8 co * 3 sel * 8 b) = 1536
    mm<0, 0, false, 512, 512, 3><<<1536, 256, 0, stream>>>(
        q_w, k_w, v_w, xs, q_bn, k_bn, v_bn, nullptr, nullptr, nullptr, qs, ks, vs);

    // 3. kv_raw = rowwise dot(k, v); 4. talking heads + lif -> kvs (float 0/1)
    kv_reduce<<<(T_STEPS * B_SZ * C_IN) / 4, 256, 0, stream>>>(ks, vs, kvraw);
    th_lif<<<(B_SZ * C_IN) / 256, 256, 0, stream>>>(kvraw, th_w, kvsf);

    // 5. xout = bn(proj(q * kvs) + b) + x  -> d_out (f32);  grid 8*(8*8)=512
    mm<1, 1, true, 512, 512, 1><<<512, 256, 0, stream>>>(
        proj_w, nullptr, nullptr, qs, proj_bn, nullptr, nullptr, proj_b, kvsf, x,
        out, nullptr, nullptr);

    // 6. hdn = lif(bn(fc1(xout) + b))  -> u8 spikes in ws;  grid 8*(32*8)=2048
    mm<0, 2, true, 512, 2048, 1><<<2048, 256, 0, stream>>>(
        fc1_w, nullptr, nullptr, out, fc1_bn, nullptr, nullptr, fc1_b, nullptr, nullptr,
        hdn, nullptr, nullptr);

    // 7. out = lif(bn(fc2(hdn) + b)) + xout  (in place on d_out);  grid 512
    mm<2, 0, true, 2048, 512, 1><<<512, 256, 0, stream>>>(
        fc2_w, nullptr, nullptr, hdn, fc2_bn, nullptr, nullptr, fc2_b, nullptr, nullptr,
        out, nullptr, nullptr);
}

// Round 9
// 2641.221 us; speedup vs baseline: 1.5064x; 1.5064x over previous
//
#include <hip/hip_runtime.h>

typedef unsigned char u8;
typedef unsigned int u32;

#define T_STEPS 4
#define B_SZ 8
#define C_IN 512
#define CH 2048
#define N_SP 1024
#define S_C ((size_t)B_SZ * C_IN * N_SP)    // elems per timestep

// ---------------------------------------------------------------------------
// lif_x: x [T,B,C,N] fp32 -> xs u8 spikes, same flat layout (round-2 verbatim).
// ---------------------------------------------------------------------------
__global__ __launch_bounds__(256) void lif_x_kernel(const float* __restrict__ in,
                                                    u8* __restrict__ out)
{
    size_t i = (size_t)blockIdx.x * 256 + threadIdx.x;
    float v = 0.0f;
    #pragma unroll
    for (int t = 0; t < T_STEPS; ++t) {
        float x = in[(size_t)t * S_C + i];
        v += (x - v) * 0.5f;
        u8 s = (v >= 0.5f) ? 1 : 0;
        out[(size_t)t * S_C + i] = s;
        v = s ? 0.0f : v;
    }
}

// ---------------------------------------------------------------------------
// Fused GEMM + BN (+bias) + LIF, fp32. Per-output math is ascending-k with a
// single fp32 accumulator -> bit-identical to the round-2/6/7 passing kernels.
// Layouts: X [TB][K][N], W [CO][K] fp32, Y [TB][CO][N].
// MODE 0: LIF -> u8 spikes. MODE 1: y + res -> f32. MODE 2: LIF spike + in-place res -> f32.
// BSRC 0: u8 X. BSRC 1: u8 X * kvsf[k] at staging (proj mask). BSRC 2: f32 X (fc1).
// Tile 64co x 128n, 256 threads, per-thread 4co x 8n (two float4 n-chunks at
// tx*4 and tx*4+64 -> 2-way LDS bank aliasing only). Register prefetch of the
// next k-tile; u8 unpack at staging. nblk = bid & 7 pins n-slices to XCDs.
// NOTE: no min-waves launch_bounds hint — round 8 proved (256,4) forces a
// 64-VGPR clamp and spills acc/vst to scratch (4.8 GB writes/dispatch).
// ---------------------------------------------------------------------------
template<int MODE, int BSRC, bool BIAS, int K, int CO, int NSEL>
__global__ __launch_bounds__(256) void mm(
    const float* __restrict__ W0, const float* __restrict__ W1, const float* __restrict__ W2,
    const void* __restrict__ Xv,
    const float* __restrict__ bn0, const float* __restrict__ bn1, const float* __restrict__ bn2,
    const float* __restrict__ bias,
    const float* __restrict__ kvsf,
    const float* __restrict__ res,
    void* Y0, void* Y1, void* Y2)
{
    constexpr int BM = 64;
    constexpr int NB_CO = CO / BM;
    constexpr int KT = K / 16;

    __shared__ float As[16][72];      // [k][co]  (stride 72: 2-way reads, free)
    __shared__ float Xs[16][136];     // [k][n]   (stride 136)

    const int bid = blockIdx.x;
    const int nblk = bid & 7;         // XCD-pinned n-slice
    int slot = bid >> 3;
    const int cb = slot % NB_CO; slot /= NB_CO;
    const int sel = (NSEL > 1) ? (slot % NSEL) : 0;
    const int b   = (NSEL > 1) ? (slot / NSEL) : slot;

    const float* W   = (NSEL == 1 || sel == 0) ? W0  : (sel == 1 ? W1  : W2);
    const float* bnp = (NSEL == 1 || sel == 0) ? bn0 : (sel == 1 ? bn1 : bn2);
    void* Yv         = (NSEL == 1 || sel == 0) ? Y0  : (sel == 1 ? Y1  : Y2);

    const int coBase = cb * BM;
    const int n0blk = nblk * 128;
    const int tid = threadIdx.x;
    const int tx = tid & 15, ty = tid >> 4;

    // staging indices: W rows by tid>>2, X row = ty, X cols = tx*4 / tx*4+64
    const int wr = tid >> 2;
    const int wk4 = (tid & 3) * 4;

    // BN constants (round-2 expressions)
    float scale[4], shift[4];
    #pragma unroll
    for (int i = 0; i < 4; ++i) {
        const int co = coBase + ty * 4 + i;
        const float g = bnp[co], be = bnp[CO + co];
        const float mn = bnp[2 * CO + co], vr = bnp[3 * CO + co];
        scale[i] = g / sqrtf(vr + 1e-5f);
        shift[i] = be - mn * scale[i];
        if (BIAS) shift[i] += bias[co] * scale[i];
    }

    float vst[4][8];
    if (MODE != 1) {
        #pragma unroll
        for (int i = 0; i < 4; ++i)
            #pragma unroll
            for (int j = 0; j < 8; ++j) vst[i][j] = 0.0f;
    }

    for (int t = 0; t < T_STEPS; ++t) {
        const int tb = t * B_SZ + b;
        const u8* Xu = (const u8*)Xv + (size_t)tb * K * N_SP;
        const float* Xf = (const float*)Xv + (size_t)tb * K * N_SP;

        float acc[4][8];
        #pragma unroll
        for (int i = 0; i < 4; ++i)
            #pragma unroll
            for (int j = 0; j < 8; ++j) acc[i][j] = 0.0f;

        float4 wreg;
        u32 xa, xb;
        float mreg = 1.0f;
        float4 xfa, xfb;

        auto prefetch = [&](int kt) {
            wreg = *reinterpret_cast<const float4*>(
                W + (size_t)(coBase + wr) * K + kt * 16 + wk4);
            if constexpr (BSRC <= 1) {
                const u8* xp = Xu + (size_t)(kt * 16 + ty) * N_SP + n0blk + tx * 4;
                xa = *reinterpret_cast<const u32*>(xp);
                xb = *reinterpret_cast<const u32*>(xp + 64);
                if constexpr (BSRC == 1)
                    mreg = kvsf[(size_t)tb * K + kt * 16 + ty];
            } else {
                const float* xp = Xf + (size_t)(kt * 16 + ty) * N_SP + n0blk + tx * 4;
                xfa = *reinterpret_cast<const float4*>(xp);
                xfb = *reinterpret_cast<const float4*>(xp + 64);
            }
        };

        prefetch(0);

        for (int kt = 0; kt < KT; ++kt) {
            __syncthreads();    // previous tile's compute done; LDS reusable
            As[wk4 + 0][wr] = wreg.x;
            As[wk4 + 1][wr] = wreg.y;
            As[wk4 + 2][wr] = wreg.z;
            As[wk4 + 3][wr] = wreg.w;
            if constexpr (BSRC <= 1) {
                float4 s0, s1;
                s0.x = (float)( xa        & 0xFFu);
                s0.y = (float)((xa >> 8 ) & 0xFFu);
                s0.z = (float)((xa >> 16) & 0xFFu);
                s0.w = (float)( xa >> 24        );
                s1.x = (float)( xb        & 0xFFu);
                s1.y = (float)((xb >> 8 ) & 0xFFu);
                s1.z = (float)((xb >> 16) & 0xFFu);
                s1.w = (float)( xb >> 24        );
                if constexpr (BSRC == 1) {
                    s0.x *= mreg; s0.y *= mreg; s0.z *= mreg; s0.w *= mreg;   // 0/1 x 0/1: exact
                    s1.x *= mreg; s1.y *= mreg; s1.z *= mreg; s1.w *= mreg;
                }
                *reinterpret_cast<float4*>(&Xs[ty][tx * 4]) = s0;
                *reinterpret_cast<float4*>(&Xs[ty][tx * 4 + 64]) = s1;
            } else {
                *reinterpret_cast<float4*>(&Xs[ty][tx * 4]) = xfa;
                *reinterpret_cast<float4*>(&Xs[ty][tx * 4 + 64]) = xfb;
            }
            __syncthreads();
            if (kt + 1 < KT) prefetch(kt + 1);   // overlaps with compute below

            #pragma unroll
            for (int kk = 0; kk < 16; ++kk) {
                float4 av = *reinterpret_cast<const float4*>(&As[kk][ty * 4]);
                float4 x0 = *reinterpret_cast<const float4*>(&Xs[kk][tx * 4]);
                float4 x1 = *reinterpret_cast<const float4*>(&Xs[kk][tx * 4 + 64]);
                float wa[4] = {av.x, av.y, av.z, av.w};
                float xw[8] = {x0.x, x0.y, x0.z, x0.w, x1.x, x1.y, x1.z, x1.w};
                #pragma unroll
                for (int i = 0; i < 4; ++i)
                    #pragma unroll
                    for (int j = 0; j < 8; ++j)
                        acc[i][j] += wa[i] * xw[j];   // ascending-k, single acc
            }
        }

        // epilogue for this timestep (round-2/6/7 expressions, bit-identical).
        // n positions: base (tx*4 + j) and base+64 (j = 4..7).
        #pragma unroll
        for (int i = 0; i < 4; ++i) {
            const int co = coBase + ty * 4 + i;
            const size_t base = ((size_t)tb * CO + co) * N_SP + n0blk + tx * 4;
            if constexpr (MODE == 0) {
                u32 p0 = 0, p1 = 0;
                #pragma unroll
                for (int j = 0; j < 8; ++j) {
                    const float y = acc[i][j] * scale[i] + shift[i];
                    float v = vst[i][j];
                    v += (y - v) * 0.5f;
                    const u32 s = (v >= 0.5f) ? 1u : 0u;
                    vst[i][j] = s ? 0.0f : v;
                    if (j < 4) p0 |= s << (8 * j); else p1 |= s << (8 * (j - 4));
                }
                *reinterpret_cast<u32*>((u8*)Yv + base) = p0;
                *reinterpret_cast<u32*>((u8*)Yv + base + 64) = p1;
            } else if constexpr (MODE == 1) {
                float4 r0 = *reinterpret_cast<const float4*>(res + base);
                float4 r1 = *reinterpret_cast<const float4*>(res + base + 64);
                float rr[8] = {r0.x, r0.y, r0.z, r0.w, r1.x, r1.y, r1.z, r1.w};
                float o[8];
                #pragma unroll
                for (int j = 0; j < 8; ++j)
                    o[j] = acc[i][j] * scale[i] + shift[i] + rr[j];
                float4 s0 = {o[0], o[1], o[2], o[3]};
                float4 s1 = {o[4], o[5], o[6], o[7]};
                *reinterpret_cast<float4*>((float*)Yv + base) = s0;
                *reinterpret_cast<float4*>((float*)Yv + base + 64) = s1;
            } else {
                float* op = (float*)Yv + base;
                float4 r0 = *reinterpret_cast<const float4*>(op);
                float4 r1 = *reinterpret_cast<const float4*>(op + 64);
                float rr[8] = {r0.x, r0.y, r0.z, r0.w, r1.x, r1.y, r1.z, r1.w};
                float o[8];
                #pragma unroll
                for (int j = 0; j < 8; ++j) {
                    const float y = acc[i][j] * scale[i] + shift[i];
                    float v = vst[i][j];
                    v += (y - v) * 0.5f;
                    const u32 s = (v >= 0.5f) ? 1u : 0u;
                    vst[i][j] = s ? 0.0f : v;
                    o[j] = rr[j] + (s ? 1.0f : 0.0f);
                }
                float4 s0 = {o[0], o[1], o[2], o[3]};
                float4 s1 = {o[4], o[5], o[6], o[7]};
                *reinterpret_cast<float4*>(op) = s0;
                *reinterpret_cast<float4*>(op + 64) = s1;
            }
        }
    }
}

// ---------------------------------------------------------------------------
// kv_raw[row=tb*C+c] = sum_n k*v  (exact integer; round-2 verbatim)
// ---------------------------------------------------------------------------
__global__ __launch_bounds__(256) void kv_reduce(const u8* __restrict__ ks,
                                                 const u8* __restrict__ vs,
                                                 float* __restrict__ kv)
{
    const int row = blockIdx.x * 4 + (threadIdx.x >> 6);  // [0, T*B*C)
    const int lane = threadIdx.x & 63;
    const u8* kp = ks + (size_t)row * N_SP;
    const u8* vp = vs + (size_t)row * N_SP;
    int acc = 0;
    #pragma unroll
    for (int n = 0; n < N_SP; n += 256) {
        uchar4 a = *reinterpret_cast<const uchar4*>(kp + n + lane * 4);
        uchar4 c = *reinterpret_cast<const uchar4*>(vp + n + lane * 4);
        acc += (a.x & c.x) + (a.y & c.y) + (a.z & c.z) + (a.w & c.w);
    }
    #pragma unroll
    for (int off = 32; off; off >>= 1) acc += __shfl_down(acc, off, 64);
    if (lane == 0) kv[row] = (float)acc;
}

// ---------------------------------------------------------------------------
// talking heads (8x8 over heads) + LIF -> kvs float {0,1}  (round-2 verbatim)
// ---------------------------------------------------------------------------
__global__ __launch_bounds__(256) void th_lif(const float* __restrict__ kvraw,
                                              const float* __restrict__ th,
                                              float* __restrict__ kvs)
{
    const int i = blockIdx.x * 256 + threadIdx.x;   // [0, B*C)
    const int b = i >> 9;
    const int c = i & 511;
    const int g = c >> 6;
    const int dd = c & 63;
    float v = 0.0f;
    #pragma unroll
    for (int t = 0; t < T_STEPS; ++t) {
        const float* base = kvraw + ((size_t)t * B_SZ + b) * C_IN;
        float x = 0.0f;
        #pragma unroll
        for (int hh = 0; hh < 8; ++hh)
            x += base[hh * 64 + dd] * th[g * 8 + hh];
        v += (x - v) * 0.5f;
        const float s = (v >= 0.5f) ? 1.0f : 0.0f;
        kvs[((size_t)t * B_SZ + b) * C_IN + c] = s;
        v = (s != 0.0f) ? 0.0f : v;
    }
}

extern "C" void kernel_launch(void* const* d_in, const int* in_sizes, int n_in,
                              void* d_out, int out_size, void* d_ws, size_t ws_size,
                              hipStream_t stream)
{
    const float* x       = (const float*)d_in[0];
    const float* q_w     = (const float*)d_in[1];
    const float* q_bn    = (const float*)d_in[2];
    const float* k_w     = (const float*)d_in[3];
    const float* k_bn    = (const float*)d_in[4];
    const float* v_w     = (const float*)d_in[5];
    const float* v_bn    = (const float*)d_in[6];
    const float* th_w    = (const float*)d_in[7];
    const float* proj_w  = (const float*)d_in[8];
    const float* proj_b  = (const float*)d_in[9];
    const float* proj_bn = (const float*)d_in[10];
    const float* fc1_w   = (const float*)d_in[11];
    const float* fc1_b   = (const float*)d_in[12];
    const float* fc1_bn  = (const float*)d_in[13];
    const float* fc2_w   = (const float*)d_in[14];
    const float* fc2_b   = (const float*)d_in[15];
    const float* fc2_bn  = (const float*)d_in[16];
    float* out = (float*)d_out;

    // workspace: round-2/6/7's proven 64 MiB + 128 KiB map
    u8* ws = (u8*)d_ws;
    const size_t SLOT = (size_t)T_STEPS * S_C;        // 16 MiB per u8 slot
    u8* xs = ws;                    // [TB][C][N] u8
    u8* qs = ws + SLOT;
    u8* ks = ws + 2 * SLOT;
    u8* vs = ws + 3 * SLOT;
    float* kvraw = (float*)(ws + 4 * SLOT);                 // [TB][C] f32 (64 KiB)
    float* kvsf  = kvraw + (size_t)T_STEPS * B_SZ * C_IN;   // [TB][C] f32 (64 KiB)
    u8* hdn = ws;                   // [TB][Ch][N] u8 = 64 MiB, reuses xs..vs (dead by fc1)

    // 1. xs = lif(x)
    lif_x_kernel<<<(int)(S_C / 256), 256, 0, stream>>>(x, xs);

    // 2. q/k/v = lif(bn(conv(xs)))  — fused triple GEMM
    //    grid = 8 n-slices * (8 co * 3 sel * 8 b) = 1536
    mm<0, 0, false, 512, 512, 3><<<1536, 256, 0, stream>>>(
        q_w, k_w, v_w, xs, q_bn, k_bn, v_bn, nullptr, nullptr, nullptr, qs, ks, vs);

    // 3. kv_raw = rowwise dot(k, v); 4. talking heads + lif -> kvs (float 0/1)
    kv_reduce<<<(T_STEPS * B_SZ * C_IN) / 4, 256, 0, stream>>>(ks, vs, kvraw);
    th_lif<<<(B_SZ * C_IN) / 256, 256, 0, stream>>>(kvraw, th_w, kvsf);

    // 5. xout = bn(proj(q * kvs) + b) + x  -> d_out (f32);  grid 8*(8*8)=512
    mm<1, 1, true, 512, 512, 1><<<512, 256, 0, stream>>>(
        proj_w, nullptr, nullptr, qs, proj_bn, nullptr, nullptr, proj_b, kvsf, x,
        out, nullptr, nullptr);

    // 6. hdn = lif(bn(fc1(xout) + b))  -> u8 spikes in ws;  grid 8*(32*8)=2048
    mm<0, 2, true, 512, 2048, 1><<<2048, 256, 0, stream>>>(
        fc1_w, nullptr, nullptr, out, fc1_bn, nullptr, nullptr, fc1_b, nullptr, nullptr,
        hdn, nullptr, nullptr);

    // 7. out = lif(bn(fc2(hdn) + b)) + xout  (in place on d_out);  grid 512
    mm<2, 0, true, 2048, 512, 1><<<512, 256, 0, stream>>>(
        fc2_w, nullptr, nullptr, hdn, fc2_bn, nullptr, nullptr, fc2_b, nullptr, nullptr,
        out, nullptr, nullptr);
}